// Round 16
// baseline (141.383 us; speedup 1.0000x reference)
//
#include <hip/hip_runtime.h>

typedef __attribute__((ext_vector_type(8))) short bf16x8;
typedef __attribute__((ext_vector_type(4))) float f32x4;
typedef __attribute__((ext_vector_type(4))) unsigned short u16x4;

#define HW_ 16384
#define LDSTR 128     // 64 bf16 * 2B, no pad; full-row XOR swizzle (R11-proven)
#define TILEB 8192    // one 64-px x 64-ch bf16 tile
#define AGGB  32768   // separate aggT buffer; total LDS 40960 = 4 blocks/CU

__device__ __forceinline__ float bf2f(unsigned short u) {
  union { unsigned u; float f; } x; x.u = ((unsigned)u) << 16; return x.f;
}
__device__ __forceinline__ unsigned short f2bf(float f) {
  union { float f; unsigned u; } x; x.f = f;
  unsigned r = x.u + 0x7fffu + ((x.u >> 16) & 1u);
  return (unsigned short)(r >> 16);
}
// XOR-swizzle: 16-B groups within each 128-B row permuted by row&7 (R11 layout:
// measured 5.2M conflict cycles vs 12.1M for the padded-144 layout).
__device__ __forceinline__ int swz(int row, int cb) {
  return row * LDSTR + (cb ^ ((row & 7) << 4));
}

#define MFMA(a, b, c) __builtin_amdgcn_mfma_f32_16x16x32_bf16(a, b, c, 0, 0, 0)

// (256,4): engineered fit — LDS 40960x4 = 160KiB exactly; unified reg demand
// reduced to ~115 (two-round v[8] staging instead of v[16]; xB held but aggT
// separate). Spill tripwire: WRITE_SIZE must stay ~274MB (R9's spill showed
// +170MB scratch writes).
__global__ __launch_bounds__(256, 4) void gci_kernel(
    const float* __restrict__ x1, const float* __restrict__ x2,
    const float* __restrict__ x3, const float* __restrict__ x4,
    const float* __restrict__ wI, const float* __restrict__ bI,
    const float* __restrict__ wS, const float* __restrict__ bS,
    const float* __restrict__ wG, const float* __restrict__ bG,
    float* __restrict__ out)
{
  // xT0..xT3 at i*TILEB, aggT at AGGB (40960 B)
  __shared__ __align__(16) char ldsb[5 * TILEB];

  const int t    = threadIdx.x;
  const int lane = t & 63;
  const int w    = t >> 6;       // wave id == output-channel group (16 ch)
  const int lr   = lane & 15;
  const int lg   = lane >> 4;

  const int pix0 = blockIdx.x * 64;
  const int b    = pix0 >> 14;          // image index (HW = 16384)
  const int pimg = pix0 & (HW_ - 1);    // pixel offset within image

  const float* xin[4] = {x1, x2, x3, x4};

  // ---------- stage x1..x4 transposed (bf16) into LDS ----------
  // thread: 4 ch x 4 px, two rounds of 8 loads (peak 32 regs, not 64).
  {
    const int pxg = (t & 15) * 4;       // px base
    const int c0  = (t >> 4) * 4;       // channel base
    #pragma unroll
    for (int half = 0; half < 2; ++half) {
      f32x4 v[8];
      #pragma unroll
      for (int i2 = 0; i2 < 2; ++i2)
        #pragma unroll
        for (int d = 0; d < 4; ++d)
          v[i2 * 4 + d] = *reinterpret_cast<const f32x4*>(
              xin[half * 2 + i2] + (b * 64 + c0 + d) * HW_ + pimg + pxg);
      #pragma unroll
      for (int i2 = 0; i2 < 2; ++i2)
        #pragma unroll
        for (int j = 0; j < 4; ++j) {
          u16x4 pk;
          #pragma unroll
          for (int d = 0; d < 4; ++d) pk[d] = f2bf(v[i2 * 4 + d][j]);
          *(u16x4*)(ldsb + (half * 2 + i2) * TILEB + swz(pxg + j, c0 * 2)) = pk;
        }
    }
  }

  // ---------- this wave's weights: 16 output channels (rows w*16..+15) ----------
  bf16x8 fWi[2], fD[2], fG1[2], fG2[2];
  #pragma unroll
  for (int kk = 0; kk < 2; ++kk) {
    const int row = w * 16 + lr, col = kk * 32 + lg * 8;
    f32x4 wa = *(const f32x4*)(wI + row * 64 + col);
    f32x4 wb = *(const f32x4*)(wI + row * 64 + col + 4);
    f32x4 sa = *(const f32x4*)(wS + row * 64 + col);
    f32x4 sb = *(const f32x4*)(wS + row * 64 + col + 4);
    f32x4 ga = *(const f32x4*)(wG + row * 128 + col);
    f32x4 gb = *(const f32x4*)(wG + row * 128 + col + 4);
    f32x4 ha = *(const f32x4*)(wG + row * 128 + 64 + col);
    f32x4 hb = *(const f32x4*)(wG + row * 128 + 64 + col + 4);
    #pragma unroll
    for (int j = 0; j < 4; ++j) {
      fWi[kk][j]     = (short)f2bf(wa[j]);
      fWi[kk][j + 4] = (short)f2bf(wb[j]);
      fD[kk][j]      = (short)f2bf(sa[j] - wa[j]);
      fD[kk][j + 4]  = (short)f2bf(sb[j] - wb[j]);
      fG1[kk][j]     = (short)f2bf(ga[j]);
      fG1[kk][j + 4] = (short)f2bf(gb[j]);
      fG2[kk][j]     = (short)f2bf(ha[j]);
      fG2[kk][j + 4] = (short)f2bf(hb[j]);
    }
  }

  // biases: C/D row = lg*4 + r  ->  ch = w*16 + lg*4 + r
  f32x4 biasA0, biasG;
  #pragma unroll
  for (int r = 0; r < 4; ++r) {
    const int ch = w * 16 + lg * 4 + r;
    biasA0[r] = bS[ch] + 3.f * bI[ch];
    biasG[r]  = bG[ch];
  }

  __syncthreads();

  // ---------- Abase[g] = Sum_i Wi*x_i + bias, via MFMA ----------
  f32x4 Abase[4];
  #pragma unroll
  for (int g = 0; g < 4; ++g) {
    Abase[g] = biasA0;
    #pragma unroll
    for (int i = 0; i < 4; ++i) {
      #pragma unroll
      for (int kk = 0; kk < 2; ++kk) {
        bf16x8 f = *(const bf16x8*)(ldsb + i * TILEB + swz(g * 16 + lr, kk * 64 + lg * 16));
        Abase[g] = MFMA(fWi[kk], f, Abase[g]);
      }
    }
  }

  // ---------- per tensor: agg -> aggT -> gate -> store ----------
  #pragma unroll
  for (int i = 0; i < 4; ++i) {
    char* tb = ldsb + i * TILEB;
    char* ab = ldsb + AGGB;

    // B-frags for all 4 px-groups (x-tiles stay intact; held through gate)
    bf16x8 xB[4][2];
    #pragma unroll
    for (int g = 0; g < 4; ++g)
      #pragma unroll
      for (int kk = 0; kk < 2; ++kk)
        xB[g][kk] = *(const bf16x8*)(tb + swz(g * 16 + lr, kk * 64 + lg * 16));

    // residual pre-read: lane = px, channels (w*16+2j, w*16+2j+1)
    unsigned xrp[8];
    #pragma unroll
    for (int j = 0; j < 8; ++j)
      xrp[j] = *(const unsigned*)(tb + swz(lane, w * 32 + 4 * j));

    // agg = relu(D * x_i + Abase)
    f32x4 agg[4];
    #pragma unroll
    for (int g = 0; g < 4; ++g) {
      agg[g] = Abase[g];
      #pragma unroll
      for (int kk = 0; kk < 2; ++kk) agg[g] = MFMA(fD[kk], xB[g][kk], agg[g]);
    }

    // write relu(agg) bf16 to aggT (prev tensor's aggT readers passed the
    // end-of-iteration barrier)
    #pragma unroll
    for (int g = 0; g < 4; ++g) {
      u16x4 pk;
      #pragma unroll
      for (int r = 0; r < 4; ++r) pk[r] = f2bf(fmaxf(agg[g][r], 0.f));
      *(u16x4*)(ab + swz(g * 16 + lr, w * 32 + lg * 8)) = pk;
    }

    __syncthreads();   // aggT complete (all 64 channels)

    // gate: out = x + Wg1*x + Wg2*agg + b_gate
    f32x4 og[4];
    #pragma unroll
    for (int g = 0; g < 4; ++g) {
      bf16x8 aB[2];
      #pragma unroll
      for (int kk = 0; kk < 2; ++kk)
        aB[kk] = *(const bf16x8*)(ab + swz(g * 16 + lr, kk * 64 + lg * 16));
      og[g] = biasG;
      #pragma unroll
      for (int kk = 0; kk < 2; ++kk) {
        og[g] = MFMA(fG1[kk], xB[g][kk], og[g]);
        og[g] = MFMA(fG2[kk], aB[kk], og[g]);
      }
    }

    // butterfly 4x4 (lg <-> g) transpose
    float B[4][4];
    #pragma unroll
    for (int r = 0; r < 4; ++r) {
      float X0 = og[0][r], X1 = og[1][r], X2 = og[2][r], X3 = og[3][r];
      float s01 = (lg & 1) ? X0 : X1; s01 = __shfl_xor(s01, 16, 64);
      float n0  = (lg & 1) ? s01 : X0;
      float n1  = (lg & 1) ? X1  : s01;
      float s23 = (lg & 1) ? X2 : X3; s23 = __shfl_xor(s23, 16, 64);
      float n2  = (lg & 1) ? s23 : X2;
      float n3  = (lg & 1) ? X3  : s23;
      float u02 = (lg & 2) ? n0 : n2; u02 = __shfl_xor(u02, 32, 64);
      B[r][0]   = (lg & 2) ? u02 : n0;
      B[r][2]   = (lg & 2) ? n2  : u02;
      float u13 = (lg & 2) ? n1 : n3; u13 = __shfl_xor(u13, 32, 64);
      B[r][1]   = (lg & 2) ? u13 : n1;
      B[r][3]   = (lg & 2) ? n3  : u13;
    }

    // stores: one instruction = 64 consecutive px (256 B lines)
    const int obase0 = i * 16777216 + b * 64 * HW_ + pimg;
    #pragma unroll
    for (int c = 0; c < 16; ++c) {
      float vv = B[c & 3][c >> 2]
               + bf2f((unsigned short)(xrp[c >> 1] >> ((c & 1) * 16)));
      out[obase0 + (w * 16 + c) * HW_ + lane] = vv;
    }

    __syncthreads();   // aggT free for next tensor
  }
}

extern "C" void kernel_launch(void* const* d_in, const int* in_sizes, int n_in,
                              void* d_out, int out_size, void* d_ws, size_t ws_size,
                              hipStream_t stream) {
  (void)in_sizes; (void)n_in; (void)d_ws; (void)ws_size; (void)out_size;
  gci_kernel<<<dim3(4096), dim3(256), 0, stream>>>(
      (const float*)d_in[0], (const float*)d_in[1],
      (const float*)d_in[2], (const float*)d_in[3],
      (const float*)d_in[4], (const float*)d_in[5],
      (const float*)d_in[6], (const float*)d_in[7],
      (const float*)d_in[8], (const float*)d_in[9],
      (float*)d_out);
}

// Round 17
// 118.809 us; speedup vs baseline: 1.1900x; 1.1900x over previous
//
#include <hip/hip_runtime.h>

typedef __attribute__((ext_vector_type(8))) short bf16x8;
typedef __attribute__((ext_vector_type(4))) float f32x4;
typedef __attribute__((ext_vector_type(4))) unsigned short u16x4;

#define HW_ 16384
#define LDSTR 144     // x-tiles: 72 bf16 * 2B per row (R15-proven layout)
#define TILEB 9216    // one 64-px x 64-ch bf16 x-tile
#define AGG0  36864   // agg ping-pong buffers at 36864 + p*8192 (128-stride)

__device__ __forceinline__ float bf2f(unsigned short u) {
  union { unsigned u; float f; } x; x.u = ((unsigned)u) << 16; return x.f;
}
__device__ __forceinline__ unsigned short f2bf(float f) {
  union { float f; unsigned u; } x; x.f = f;
  unsigned r = x.u + 0x7fffu + ((x.u >> 16) & 1u);
  return (unsigned short)(r >> 16);
}
// x-tile swizzle (R15): 16-B groups rotated by (row>>3)&7 within 144-B rows
__device__ __forceinline__ int swz(int row, int cb) {
  return row * LDSTR + (cb ^ (((row >> 3) & 7) << 4));
}
// agg-buffer swizzle: full-row XOR within 128-B rows (R16 layout)
__device__ __forceinline__ int swa(int row, int cb) {
  return row * 128 + (cb ^ ((row & 7) << 4));
}

#define MFMA(a, b, c) __builtin_amdgcn_mfma_f32_16x16x32_bf16(a, b, c, 0, 0, 0)

// (256,3): FINAL — 3x confirmed (R5/R9/R16) that forcing 4 waves/EU spills
// (unified VGPR+AGPR demand ~140-170 > 128 cap). R17: barrier count 9 -> 5
// via separate double-buffered agg LDS (removes the WAR barrier that existed
// only because agg overwrote the x-tile bytes).
__global__ __launch_bounds__(256, 3) void gci_kernel(
    const float* __restrict__ x1, const float* __restrict__ x2,
    const float* __restrict__ x3, const float* __restrict__ x4,
    const float* __restrict__ wI, const float* __restrict__ bI,
    const float* __restrict__ wS, const float* __restrict__ bS,
    const float* __restrict__ wG, const float* __restrict__ bG,
    float* __restrict__ out)
{
  // xT0..xT3 (4 x 9216) + agg ping-pong (2 x 8192) = 53248 B -> 3 blocks/CU
  __shared__ __align__(16) char ldsb[4 * TILEB + 2 * 8192];

  const int t    = threadIdx.x;
  const int lane = t & 63;
  const int w    = t >> 6;       // wave id == output-channel group (16 ch)
  const int lr   = lane & 15;
  const int lg   = lane >> 4;

  const int pix0 = blockIdx.x * 64;
  const int b    = pix0 >> 14;          // image index (HW = 16384)
  const int pimg = pix0 & (HW_ - 1);    // pixel offset within image

  const float* xin[4] = {x1, x2, x3, x4};

  // ---------- stage x1..x4 transposed (bf16) into LDS (R15-proven) ----------
  // thread: 4 channels x 4 px; 16 loads issued, then 16 ds_write_b64.
  {
    const int pxg = (t & 15) * 4;       // px base
    const int c0  = (t >> 4) * 4;       // channel base
    f32x4 v[16];
    #pragma unroll
    for (int i = 0; i < 4; ++i)
      #pragma unroll
      for (int d = 0; d < 4; ++d)
        v[i * 4 + d] = *reinterpret_cast<const f32x4*>(
            xin[i] + (b * 64 + c0 + d) * HW_ + pimg + pxg);
    #pragma unroll
    for (int i = 0; i < 4; ++i)
      #pragma unroll
      for (int j = 0; j < 4; ++j) {
        u16x4 pk;
        #pragma unroll
        for (int d = 0; d < 4; ++d) pk[d] = f2bf(v[i * 4 + d][j]);
        *(u16x4*)(ldsb + i * TILEB + swz(pxg + j, c0 * 2)) = pk;
      }
  }

  // ---------- this wave's weights: 16 output channels (rows w*16..+15) ----------
  bf16x8 fWi[2], fD[2], fG1[2], fG2[2];
  #pragma unroll
  for (int kk = 0; kk < 2; ++kk) {
    const int row = w * 16 + lr, col = kk * 32 + lg * 8;
    f32x4 wa = *(const f32x4*)(wI + row * 64 + col);
    f32x4 wb = *(const f32x4*)(wI + row * 64 + col + 4);
    f32x4 sa = *(const f32x4*)(wS + row * 64 + col);
    f32x4 sb = *(const f32x4*)(wS + row * 64 + col + 4);
    f32x4 ga = *(const f32x4*)(wG + row * 128 + col);
    f32x4 gb = *(const f32x4*)(wG + row * 128 + col + 4);
    f32x4 ha = *(const f32x4*)(wG + row * 128 + 64 + col);
    f32x4 hb = *(const f32x4*)(wG + row * 128 + 64 + col + 4);
    #pragma unroll
    for (int j = 0; j < 4; ++j) {
      fWi[kk][j]     = (short)f2bf(wa[j]);
      fWi[kk][j + 4] = (short)f2bf(wb[j]);
      fD[kk][j]      = (short)f2bf(sa[j] - wa[j]);
      fD[kk][j + 4]  = (short)f2bf(sb[j] - wb[j]);
      fG1[kk][j]     = (short)f2bf(ga[j]);
      fG1[kk][j + 4] = (short)f2bf(gb[j]);
      fG2[kk][j]     = (short)f2bf(ha[j]);
      fG2[kk][j + 4] = (short)f2bf(hb[j]);
    }
  }

  // biases: C/D row = lg*4 + r  ->  ch = w*16 + lg*4 + r
  f32x4 biasA0, biasG;
  #pragma unroll
  for (int r = 0; r < 4; ++r) {
    const int ch = w * 16 + lg * 4 + r;
    biasA0[r] = bS[ch] + 3.f * bI[ch];
    biasG[r]  = bG[ch];
  }

  __syncthreads();   // barrier 1 of 5: x-tiles published

  // ---------- Abase[g] = Sum_i Wi*x_i + bias, via MFMA ----------
  f32x4 Abase[4];
  #pragma unroll
  for (int g = 0; g < 4; ++g) {
    Abase[g] = biasA0;
    #pragma unroll
    for (int i = 0; i < 4; ++i) {
      #pragma unroll
      for (int kk = 0; kk < 2; ++kk) {
        bf16x8 f = *(const bf16x8*)(ldsb + i * TILEB + swz(g * 16 + lr, kk * 64 + lg * 16));
        Abase[g] = MFMA(fWi[kk], f, Abase[g]);
      }
    }
  }

  // ---------- per tensor: agg -> aggT(dbuf) -> 1 barrier -> gate -> store ----------
  #pragma unroll
  for (int i = 0; i < 4; ++i) {
    char* tb = ldsb + i * TILEB;
    char* ab = ldsb + AGG0 + (i & 1) * 8192;   // ping-pong: safe with 1 barrier
                                               // (rewrite of buffer p at i+2 is
                                               //  fenced by barrier at i+1)

    // x B-frags (x-tiles immutable now; held through gate)
    bf16x8 xB[4][2];
    #pragma unroll
    for (int g = 0; g < 4; ++g)
      #pragma unroll
      for (int kk = 0; kk < 2; ++kk)
        xB[g][kk] = *(const bf16x8*)(tb + swz(g * 16 + lr, kk * 64 + lg * 16));

    // residual: lane = px, channels (w*16+2j, w*16+2j+1) — tile never overwritten
    unsigned xrp[8];
    #pragma unroll
    for (int j = 0; j < 8; ++j)
      xrp[j] = *(const unsigned*)(tb + swz(lane, w * 32 + 4 * j));

    // agg = relu(D * x_i + Abase)
    f32x4 agg[4];
    #pragma unroll
    for (int g = 0; g < 4; ++g) {
      agg[g] = Abase[g];
      #pragma unroll
      for (int kk = 0; kk < 2; ++kk) agg[g] = MFMA(fD[kk], xB[g][kk], agg[g]);
    }

    // write relu(agg) bf16 to agg buffer (our 16 ch columns, all px rows)
    #pragma unroll
    for (int g = 0; g < 4; ++g) {
      u16x4 pk;
      #pragma unroll
      for (int r = 0; r < 4; ++r) pk[r] = f2bf(fmaxf(agg[g][r], 0.f));
      *(u16x4*)(ab + swa(g * 16 + lr, w * 32 + lg * 8)) = pk;
    }

    __syncthreads();   // the ONLY barrier per tensor: agg published

    // gate: out = x + Wg1*x + Wg2*agg + b_gate
    f32x4 og[4];
    #pragma unroll
    for (int g = 0; g < 4; ++g) {
      bf16x8 aB[2];
      #pragma unroll
      for (int kk = 0; kk < 2; ++kk)
        aB[kk] = *(const bf16x8*)(ab + swa(g * 16 + lr, kk * 64 + lg * 16));
      og[g] = biasG;
      #pragma unroll
      for (int kk = 0; kk < 2; ++kk) {
        og[g] = MFMA(fG1[kk], xB[g][kk], og[g]);
        og[g] = MFMA(fG2[kk], aB[kk], og[g]);
      }
    }

    // butterfly 4x4 (lg <-> g) transpose
    float B[4][4];
    #pragma unroll
    for (int r = 0; r < 4; ++r) {
      float X0 = og[0][r], X1 = og[1][r], X2 = og[2][r], X3 = og[3][r];
      float s01 = (lg & 1) ? X0 : X1; s01 = __shfl_xor(s01, 16, 64);
      float n0  = (lg & 1) ? s01 : X0;
      float n1  = (lg & 1) ? X1  : s01;
      float s23 = (lg & 1) ? X2 : X3; s23 = __shfl_xor(s23, 16, 64);
      float n2  = (lg & 1) ? s23 : X2;
      float n3  = (lg & 1) ? X3  : s23;
      float u02 = (lg & 2) ? n0 : n2; u02 = __shfl_xor(u02, 32, 64);
      B[r][0]   = (lg & 2) ? u02 : n0;
      B[r][2]   = (lg & 2) ? n2  : u02;
      float u13 = (lg & 2) ? n1 : n3; u13 = __shfl_xor(u13, 32, 64);
      B[r][1]   = (lg & 2) ? u13 : n1;
      B[r][3]   = (lg & 2) ? n3  : u13;
    }

    // stores: one instruction = 64 consecutive px (256 B lines)
    const int obase0 = i * 16777216 + b * 64 * HW_ + pimg;
    #pragma unroll
    for (int c = 0; c < 16; ++c) {
      float vv = B[c & 3][c >> 2]
               + bf2f((unsigned short)(xrp[c >> 1] >> ((c & 1) * 16)));
      out[obase0 + (w * 16 + c) * HW_ + lane] = vv;
    }
  }
}

extern "C" void kernel_launch(void* const* d_in, const int* in_sizes, int n_in,
                              void* d_out, int out_size, void* d_ws, size_t ws_size,
                              hipStream_t stream) {
  (void)in_sizes; (void)n_in; (void)d_ws; (void)ws_size; (void)out_size;
  gci_kernel<<<dim3(4096), dim3(256), 0, stream>>>(
      (const float*)d_in[0], (const float*)d_in[1],
      (const float*)d_in[2], (const float*)d_in[3],
      (const float*)d_in[4], (const float*)d_in[5],
      (const float*)d_in[6], (const float*)d_in[7],
      (const float*)d_in[8], (const float*)d_in[9],
      (float*)d_out);
}

// Round 18
// 95.618 us; speedup vs baseline: 1.4786x; 1.2425x over previous
//
#include <hip/hip_runtime.h>

typedef __attribute__((ext_vector_type(8))) short bf16x8;
typedef __attribute__((ext_vector_type(4))) float f32x4;
typedef __attribute__((ext_vector_type(4))) unsigned short u16x4;

#define HW_ 16384
#define LDSTR 144     // x-tiles: 72 bf16 * 2B per row (R15-proven layout)
#define TILEB 9216    // one 64-px x 64-ch bf16 x-tile
#define AGG0  36864   // agg ping-pong buffers at 36864 + p*8192 (128-stride)

__device__ __forceinline__ float bf2f(unsigned short u) {
  union { unsigned u; float f; } x; x.u = ((unsigned)u) << 16; return x.f;
}
__device__ __forceinline__ unsigned short f2bf(float f) {
  union { float f; unsigned u; } x; x.f = f;
  unsigned r = x.u + 0x7fffu + ((x.u >> 16) & 1u);
  return (unsigned short)(r >> 16);
}
// x-tile swizzle (R15): 16-B groups rotated by (row>>3)&7 within 144-B rows
__device__ __forceinline__ int swz(int row, int cb) {
  return row * LDSTR + (cb ^ (((row >> 3) & 7) << 4));
}
// agg-buffer swizzle: full-row XOR within 128-B rows
__device__ __forceinline__ int swa(int row, int cb) {
  return row * 128 + (cb ^ ((row & 7) << 4));
}

#define MFMA(a, b, c) __builtin_amdgcn_mfma_f32_16x16x32_bf16(a, b, c, 0, 0, 0)

// (256,3): FINAL occupancy point — 3x confirmed (R5/R9/R16) that 4 waves/EU
// spills. R18: (a) hoist the barrier-independent fG1*x MFMAs into the
// pre-barrier phase (halves the post-barrier critical path, fills the
// agg-write->barrier window); (b) nontemporal stores (output is write-once;
// keep L2 for input residency).
__global__ __launch_bounds__(256, 3) void gci_kernel(
    const float* __restrict__ x1, const float* __restrict__ x2,
    const float* __restrict__ x3, const float* __restrict__ x4,
    const float* __restrict__ wI, const float* __restrict__ bI,
    const float* __restrict__ wS, const float* __restrict__ bS,
    const float* __restrict__ wG, const float* __restrict__ bG,
    float* __restrict__ out)
{
  // xT0..xT3 (4 x 9216) + agg ping-pong (2 x 8192) = 53248 B -> 3 blocks/CU
  __shared__ __align__(16) char ldsb[4 * TILEB + 2 * 8192];

  const int t    = threadIdx.x;
  const int lane = t & 63;
  const int w    = t >> 6;       // wave id == output-channel group (16 ch)
  const int lr   = lane & 15;
  const int lg   = lane >> 4;

  const int pix0 = blockIdx.x * 64;
  const int b    = pix0 >> 14;          // image index (HW = 16384)
  const int pimg = pix0 & (HW_ - 1);    // pixel offset within image

  const float* xin[4] = {x1, x2, x3, x4};

  // ---------- stage x1..x4 transposed (bf16) into LDS (R15-proven) ----------
  {
    const int pxg = (t & 15) * 4;       // px base
    const int c0  = (t >> 4) * 4;       // channel base
    f32x4 v[16];
    #pragma unroll
    for (int i = 0; i < 4; ++i)
      #pragma unroll
      for (int d = 0; d < 4; ++d)
        v[i * 4 + d] = *reinterpret_cast<const f32x4*>(
            xin[i] + (b * 64 + c0 + d) * HW_ + pimg + pxg);
    #pragma unroll
    for (int i = 0; i < 4; ++i)
      #pragma unroll
      for (int j = 0; j < 4; ++j) {
        u16x4 pk;
        #pragma unroll
        for (int d = 0; d < 4; ++d) pk[d] = f2bf(v[i * 4 + d][j]);
        *(u16x4*)(ldsb + i * TILEB + swz(pxg + j, c0 * 2)) = pk;
      }
  }

  // ---------- this wave's weights: 16 output channels (rows w*16..+15) ----------
  bf16x8 fWi[2], fD[2], fG1[2], fG2[2];
  #pragma unroll
  for (int kk = 0; kk < 2; ++kk) {
    const int row = w * 16 + lr, col = kk * 32 + lg * 8;
    f32x4 wa = *(const f32x4*)(wI + row * 64 + col);
    f32x4 wb = *(const f32x4*)(wI + row * 64 + col + 4);
    f32x4 sa = *(const f32x4*)(wS + row * 64 + col);
    f32x4 sb = *(const f32x4*)(wS + row * 64 + col + 4);
    f32x4 ga = *(const f32x4*)(wG + row * 128 + col);
    f32x4 gb = *(const f32x4*)(wG + row * 128 + col + 4);
    f32x4 ha = *(const f32x4*)(wG + row * 128 + 64 + col);
    f32x4 hb = *(const f32x4*)(wG + row * 128 + 64 + col + 4);
    #pragma unroll
    for (int j = 0; j < 4; ++j) {
      fWi[kk][j]     = (short)f2bf(wa[j]);
      fWi[kk][j + 4] = (short)f2bf(wb[j]);
      fD[kk][j]      = (short)f2bf(sa[j] - wa[j]);
      fD[kk][j + 4]  = (short)f2bf(sb[j] - wb[j]);
      fG1[kk][j]     = (short)f2bf(ga[j]);
      fG1[kk][j + 4] = (short)f2bf(gb[j]);
      fG2[kk][j]     = (short)f2bf(ha[j]);
      fG2[kk][j + 4] = (short)f2bf(hb[j]);
    }
  }

  // biases: C/D row = lg*4 + r  ->  ch = w*16 + lg*4 + r
  f32x4 biasA0, biasG;
  #pragma unroll
  for (int r = 0; r < 4; ++r) {
    const int ch = w * 16 + lg * 4 + r;
    biasA0[r] = bS[ch] + 3.f * bI[ch];
    biasG[r]  = bG[ch];
  }

  __syncthreads();   // barrier 1 of 5: x-tiles published

  // ---------- Abase[g] = Sum_i Wi*x_i + bias, via MFMA ----------
  f32x4 Abase[4];
  #pragma unroll
  for (int g = 0; g < 4; ++g) {
    Abase[g] = biasA0;
    #pragma unroll
    for (int i = 0; i < 4; ++i) {
      #pragma unroll
      for (int kk = 0; kk < 2; ++kk) {
        bf16x8 f = *(const bf16x8*)(ldsb + i * TILEB + swz(g * 16 + lr, kk * 64 + lg * 16));
        Abase[g] = MFMA(fWi[kk], f, Abase[g]);
      }
    }
  }

  // ---------- per tensor: [agg + Wg1*x] -> barrier -> [Wg2*agg] -> store ----------
  #pragma unroll
  for (int i = 0; i < 4; ++i) {
    char* tb = ldsb + i * TILEB;
    char* ab = ldsb + AGG0 + (i & 1) * 8192;   // ping-pong agg buffer

    // x B-frags (x-tiles immutable; held through gate)
    bf16x8 xB[4][2];
    #pragma unroll
    for (int g = 0; g < 4; ++g)
      #pragma unroll
      for (int kk = 0; kk < 2; ++kk)
        xB[g][kk] = *(const bf16x8*)(tb + swz(g * 16 + lr, kk * 64 + lg * 16));

    // residual: lane = px, channels (w*16+2j, w*16+2j+1)
    unsigned xrp[8];
    #pragma unroll
    for (int j = 0; j < 8; ++j)
      xrp[j] = *(const unsigned*)(tb + swz(lane, w * 32 + 4 * j));

    // agg = relu(D * x_i + Abase)
    f32x4 agg[4];
    #pragma unroll
    for (int g = 0; g < 4; ++g) {
      agg[g] = Abase[g];
      #pragma unroll
      for (int kk = 0; kk < 2; ++kk) agg[g] = MFMA(fD[kk], xB[g][kk], agg[g]);
    }

    // publish relu(agg) to agg buffer
    #pragma unroll
    for (int g = 0; g < 4; ++g) {
      u16x4 pk;
      #pragma unroll
      for (int r = 0; r < 4; ++r) pk[r] = f2bf(fmaxf(agg[g][r], 0.f));
      *(u16x4*)(ab + swa(g * 16 + lr, w * 32 + lg * 8)) = pk;
    }

    // HOISTED: barrier-independent half of the gate (Wg1 * x + bias).
    // Fills the agg-write -> barrier window with MFMA work.
    f32x4 og[4];
    #pragma unroll
    for (int g = 0; g < 4; ++g) {
      og[g] = biasG;
      #pragma unroll
      for (int kk = 0; kk < 2; ++kk) og[g] = MFMA(fG1[kk], xB[g][kk], og[g]);
    }

    __syncthreads();   // agg published (the only barrier per tensor)

    // post-barrier: only the Wg2 * agg half remains on the critical path
    #pragma unroll
    for (int g = 0; g < 4; ++g) {
      bf16x8 aB[2];
      #pragma unroll
      for (int kk = 0; kk < 2; ++kk)
        aB[kk] = *(const bf16x8*)(ab + swa(g * 16 + lr, kk * 64 + lg * 16));
      #pragma unroll
      for (int kk = 0; kk < 2; ++kk) og[g] = MFMA(fG2[kk], aB[kk], og[g]);
    }

    // butterfly 4x4 (lg <-> g) transpose
    float B[4][4];
    #pragma unroll
    for (int r = 0; r < 4; ++r) {
      float X0 = og[0][r], X1 = og[1][r], X2 = og[2][r], X3 = og[3][r];
      float s01 = (lg & 1) ? X0 : X1; s01 = __shfl_xor(s01, 16, 64);
      float n0  = (lg & 1) ? s01 : X0;
      float n1  = (lg & 1) ? X1  : s01;
      float s23 = (lg & 1) ? X2 : X3; s23 = __shfl_xor(s23, 16, 64);
      float n2  = (lg & 1) ? s23 : X2;
      float n3  = (lg & 1) ? X3  : s23;
      float u02 = (lg & 2) ? n0 : n2; u02 = __shfl_xor(u02, 32, 64);
      B[r][0]   = (lg & 2) ? u02 : n0;
      B[r][2]   = (lg & 2) ? n2  : u02;
      float u13 = (lg & 2) ? n1 : n3; u13 = __shfl_xor(u13, 32, 64);
      B[r][1]   = (lg & 2) ? u13 : n1;
      B[r][3]   = (lg & 2) ? n3  : u13;
    }

    // stores: nontemporal (write-once output; keep L2 for inputs),
    // one instruction = 64 consecutive px (256 B lines)
    const int obase0 = i * 16777216 + b * 64 * HW_ + pimg;
    #pragma unroll
    for (int c = 0; c < 16; ++c) {
      float vv = B[c & 3][c >> 2]
               + bf2f((unsigned short)(xrp[c >> 1] >> ((c & 1) * 16)));
      __builtin_nontemporal_store(vv, &out[obase0 + (w * 16 + c) * HW_ + lane]);
    }
  }
}

extern "C" void kernel_launch(void* const* d_in, const int* in_sizes, int n_in,
                              void* d_out, int out_size, void* d_ws, size_t ws_size,
                              hipStream_t stream) {
  (void)in_sizes; (void)n_in; (void)d_ws; (void)ws_size; (void)out_size;
  gci_kernel<<<dim3(4096), dim3(256), 0, stream>>>(
      (const float*)d_in[0], (const float*)d_in[1],
      (const float*)d_in[2], (const float*)d_in[3],
      (const float*)d_in[4], (const float*)d_in[5],
      (const float*)d_in[6], (const float*)d_in[7],
      (const float*)d_in[8], (const float*)d_in[9],
      (float*)d_out);
}

// Round 19
// 94.865 us; speedup vs baseline: 1.4904x; 1.0079x over previous
//
#include <hip/hip_runtime.h>

typedef __attribute__((ext_vector_type(8))) short bf16x8;
typedef __attribute__((ext_vector_type(4))) float f32x4;
typedef __attribute__((ext_vector_type(4))) unsigned short u16x4;

#define HW_ 16384
#define LDSTR 144     // x-tiles: 72 bf16 * 2B per row (R15-proven layout)
#define TILEB 9216    // one 64-px x 64-ch bf16 x-tile
#define AGG0  36864   // agg ping-pong buffers at 36864 + p*8192 (128-stride)

__device__ __forceinline__ float bf2f(unsigned short u) {
  union { unsigned u; float f; } x; x.u = ((unsigned)u) << 16; return x.f;
}
__device__ __forceinline__ unsigned short f2bf(float f) {
  union { float f; unsigned u; } x; x.f = f;
  unsigned r = x.u + 0x7fffu + ((x.u >> 16) & 1u);
  return (unsigned short)(r >> 16);
}
// x-tile swizzle (R15): 16-B groups rotated by (row>>3)&7 within 144-B rows
__device__ __forceinline__ int swz(int row, int cb) {
  return row * LDSTR + (cb ^ (((row >> 3) & 7) << 4));
}
// agg-buffer swizzle: full-row XOR within 128-B rows
__device__ __forceinline__ int swa(int row, int cb) {
  return row * 128 + (cb ^ ((row & 7) << 4));
}

#define MFMA(a, b, c) __builtin_amdgcn_mfma_f32_16x16x32_bf16(a, b, c, 0, 0, 0)

// (256,3): FINAL occupancy point — 3x confirmed (R5/R9/R16) that 4 waves/EU
// spills. R19: (a) residual folded into og BEFORE the butterfly (pre-barrier
// ILP region; store tail is now pure stores); (b) next tensor's xB frags
// prefetched BEFORE the barrier (x-tiles immutable after barrier 1, so the
// reads complete during the barrier drain). Spill tripwire: WRITE ~274MB.
__global__ __launch_bounds__(256, 3) void gci_kernel(
    const float* __restrict__ x1, const float* __restrict__ x2,
    const float* __restrict__ x3, const float* __restrict__ x4,
    const float* __restrict__ wI, const float* __restrict__ bI,
    const float* __restrict__ wS, const float* __restrict__ bS,
    const float* __restrict__ wG, const float* __restrict__ bG,
    float* __restrict__ out)
{
  // xT0..xT3 (4 x 9216) + agg ping-pong (2 x 8192) = 53248 B -> 3 blocks/CU
  __shared__ __align__(16) char ldsb[4 * TILEB + 2 * 8192];

  const int t    = threadIdx.x;
  const int lane = t & 63;
  const int w    = t >> 6;       // wave id == output-channel group (16 ch)
  const int lr   = lane & 15;
  const int lg   = lane >> 4;

  const int pix0 = blockIdx.x * 64;
  const int b    = pix0 >> 14;          // image index (HW = 16384)
  const int pimg = pix0 & (HW_ - 1);    // pixel offset within image

  const float* xin[4] = {x1, x2, x3, x4};

  // ---------- stage x1..x4 transposed (bf16) into LDS (R15-proven) ----------
  {
    const int pxg = (t & 15) * 4;       // px base
    const int c0  = (t >> 4) * 4;       // channel base
    f32x4 v[16];
    #pragma unroll
    for (int i = 0; i < 4; ++i)
      #pragma unroll
      for (int d = 0; d < 4; ++d)
        v[i * 4 + d] = *reinterpret_cast<const f32x4*>(
            xin[i] + (b * 64 + c0 + d) * HW_ + pimg + pxg);
    #pragma unroll
    for (int i = 0; i < 4; ++i)
      #pragma unroll
      for (int j = 0; j < 4; ++j) {
        u16x4 pk;
        #pragma unroll
        for (int d = 0; d < 4; ++d) pk[d] = f2bf(v[i * 4 + d][j]);
        *(u16x4*)(ldsb + i * TILEB + swz(pxg + j, c0 * 2)) = pk;
      }
  }

  // ---------- this wave's weights: 16 output channels (rows w*16..+15) ----------
  bf16x8 fWi[2], fD[2], fG1[2], fG2[2];
  #pragma unroll
  for (int kk = 0; kk < 2; ++kk) {
    const int row = w * 16 + lr, col = kk * 32 + lg * 8;
    f32x4 wa = *(const f32x4*)(wI + row * 64 + col);
    f32x4 wb = *(const f32x4*)(wI + row * 64 + col + 4);
    f32x4 sa = *(const f32x4*)(wS + row * 64 + col);
    f32x4 sb = *(const f32x4*)(wS + row * 64 + col + 4);
    f32x4 ga = *(const f32x4*)(wG + row * 128 + col);
    f32x4 gb = *(const f32x4*)(wG + row * 128 + col + 4);
    f32x4 ha = *(const f32x4*)(wG + row * 128 + 64 + col);
    f32x4 hb = *(const f32x4*)(wG + row * 128 + 64 + col + 4);
    #pragma unroll
    for (int j = 0; j < 4; ++j) {
      fWi[kk][j]     = (short)f2bf(wa[j]);
      fWi[kk][j + 4] = (short)f2bf(wb[j]);
      fD[kk][j]      = (short)f2bf(sa[j] - wa[j]);
      fD[kk][j + 4]  = (short)f2bf(sb[j] - wb[j]);
      fG1[kk][j]     = (short)f2bf(ga[j]);
      fG1[kk][j + 4] = (short)f2bf(gb[j]);
      fG2[kk][j]     = (short)f2bf(ha[j]);
      fG2[kk][j + 4] = (short)f2bf(hb[j]);
    }
  }

  // biases: C/D row = lg*4 + r  ->  ch = w*16 + lg*4 + r
  f32x4 biasA0, biasG;
  #pragma unroll
  for (int r = 0; r < 4; ++r) {
    const int ch = w * 16 + lg * 4 + r;
    biasA0[r] = bS[ch] + 3.f * bI[ch];
    biasG[r]  = bG[ch];
  }

  __syncthreads();   // barrier 1 of 5: x-tiles published (immutable after)

  // ---------- Abase[g] = Sum_i Wi*x_i + bias, via MFMA ----------
  f32x4 Abase[4];
  #pragma unroll
  for (int g = 0; g < 4; ++g) {
    Abase[g] = biasA0;
    #pragma unroll
    for (int i = 0; i < 4; ++i) {
      #pragma unroll
      for (int kk = 0; kk < 2; ++kk) {
        bf16x8 f = *(const bf16x8*)(ldsb + i * TILEB + swz(g * 16 + lr, kk * 64 + lg * 16));
        Abase[g] = MFMA(fWi[kk], f, Abase[g]);
      }
    }
  }

  // tensor-0 x fragments
  bf16x8 xB[4][2];
  #pragma unroll
  for (int g = 0; g < 4; ++g)
    #pragma unroll
    for (int kk = 0; kk < 2; ++kk)
      xB[g][kk] = *(const bf16x8*)(ldsb + swz(g * 16 + lr, kk * 64 + lg * 16));

  // ---------- per tensor (software-pipelined xB) ----------
  #pragma unroll
  for (int i = 0; i < 4; ++i) {
    char* tb = ldsb + i * TILEB;
    char* ab = ldsb + AGG0 + (i & 1) * 8192;   // ping-pong agg buffer

    // residual for og[g][r]: x[g*16+lr][w*16+lg*4+r] — one b64 per g
    u16x4 xr[4];
    #pragma unroll
    for (int g = 0; g < 4; ++g)
      xr[g] = *(const u16x4*)(tb + swz(g * 16 + lr, w * 32 + lg * 8));

    // agg = relu(D * x_i + Abase)
    f32x4 agg[4];
    #pragma unroll
    for (int g = 0; g < 4; ++g) {
      agg[g] = Abase[g];
      #pragma unroll
      for (int kk = 0; kk < 2; ++kk) agg[g] = MFMA(fD[kk], xB[g][kk], agg[g]);
    }

    // publish relu(agg) to agg buffer
    #pragma unroll
    for (int g = 0; g < 4; ++g) {
      u16x4 pk;
      #pragma unroll
      for (int r = 0; r < 4; ++r) pk[r] = f2bf(fmaxf(agg[g][r], 0.f));
      *(u16x4*)(ab + swa(g * 16 + lr, w * 32 + lg * 8)) = pk;
    }

    // hoisted gate half: og = biasG + residual + Wg1*x  (barrier-independent)
    f32x4 og[4];
    #pragma unroll
    for (int g = 0; g < 4; ++g) {
      og[g] = biasG;
      #pragma unroll
      for (int r = 0; r < 4; ++r) og[g][r] += bf2f(xr[g][r]);
      #pragma unroll
      for (int kk = 0; kk < 2; ++kk) og[g] = MFMA(fG1[kk], xB[g][kk], og[g]);
    }

    // prefetch next tensor's xB BEFORE the barrier (x-tiles immutable);
    // the reads complete during the barrier drain.
    bf16x8 nxB[4][2];
    if (i < 3) {
      char* nb = ldsb + (i + 1) * TILEB;
      #pragma unroll
      for (int g = 0; g < 4; ++g)
        #pragma unroll
        for (int kk = 0; kk < 2; ++kk)
          nxB[g][kk] = *(const bf16x8*)(nb + swz(g * 16 + lr, kk * 64 + lg * 16));
    }

    __syncthreads();   // agg published (the only barrier per tensor)

    // post-barrier: only Wg2 * agg remains on the critical path
    #pragma unroll
    for (int g = 0; g < 4; ++g) {
      bf16x8 aB[2];
      #pragma unroll
      for (int kk = 0; kk < 2; ++kk)
        aB[kk] = *(const bf16x8*)(ab + swa(g * 16 + lr, kk * 64 + lg * 16));
      #pragma unroll
      for (int kk = 0; kk < 2; ++kk) og[g] = MFMA(fG2[kk], aB[kk], og[g]);
    }

    // butterfly 4x4 (lg <-> g) transpose (residual already inside og)
    float B[4][4];
    #pragma unroll
    for (int r = 0; r < 4; ++r) {
      float X0 = og[0][r], X1 = og[1][r], X2 = og[2][r], X3 = og[3][r];
      float s01 = (lg & 1) ? X0 : X1; s01 = __shfl_xor(s01, 16, 64);
      float n0  = (lg & 1) ? s01 : X0;
      float n1  = (lg & 1) ? X1  : s01;
      float s23 = (lg & 1) ? X2 : X3; s23 = __shfl_xor(s23, 16, 64);
      float n2  = (lg & 1) ? s23 : X2;
      float n3  = (lg & 1) ? X3  : s23;
      float u02 = (lg & 2) ? n0 : n2; u02 = __shfl_xor(u02, 32, 64);
      B[r][0]   = (lg & 2) ? u02 : n0;
      B[r][2]   = (lg & 2) ? n2  : u02;
      float u13 = (lg & 2) ? n1 : n3; u13 = __shfl_xor(u13, 32, 64);
      B[r][1]   = (lg & 2) ? u13 : n1;
      B[r][3]   = (lg & 2) ? n3  : u13;
    }

    // stores: pure nontemporal streams, 256 B lines
    const int obase0 = i * 16777216 + b * 64 * HW_ + pimg;
    #pragma unroll
    for (int c = 0; c < 16; ++c)
      __builtin_nontemporal_store(B[c & 3][c >> 2],
                                  &out[obase0 + (w * 16 + c) * HW_ + lane]);

    // rotate pipeline
    if (i < 3) {
      #pragma unroll
      for (int g = 0; g < 4; ++g)
        #pragma unroll
        for (int kk = 0; kk < 2; ++kk)
          xB[g][kk] = nxB[g][kk];
    }
  }
}

extern "C" void kernel_launch(void* const* d_in, const int* in_sizes, int n_in,
                              void* d_out, int out_size, void* d_ws, size_t ws_size,
                              hipStream_t stream) {
  (void)in_sizes; (void)n_in; (void)d_ws; (void)ws_size; (void)out_size;
  gci_kernel<<<dim3(4096), dim3(256), 0, stream>>>(
      (const float*)d_in[0], (const float*)d_in[1],
      (const float*)d_in[2], (const float*)d_in[3],
      (const float*)d_in[4], (const float*)d_in[5],
      (const float*)d_in[6], (const float*)d_in[7],
      (const float*)d_in[8], (const float*)d_in[9],
      (float*)d_out);
}

// Round 20
// 94.042 us; speedup vs baseline: 1.5034x; 1.0088x over previous
//
#include <hip/hip_runtime.h>

typedef __attribute__((ext_vector_type(8))) short bf16x8;
typedef __attribute__((ext_vector_type(4))) float f32x4;
typedef __attribute__((ext_vector_type(4))) unsigned short u16x4;

#define HW_ 16384
#define LDSTR 144     // x-tiles: 72 bf16 * 2B per row (R15-proven layout)
#define TILEB 9216    // one 64-px x 64-ch bf16 x-tile
#define AGG0  36864   // agg ping-pong buffers at 36864 + p*8192 (128-stride)

__device__ __forceinline__ float bf2f(unsigned short u) {
  union { unsigned u; float f; } x; x.u = ((unsigned)u) << 16; return x.f;
}
__device__ __forceinline__ unsigned short f2bf(float f) {
  union { float f; unsigned u; } x; x.f = f;
  unsigned r = x.u + 0x7fffu + ((x.u >> 16) & 1u);
  return (unsigned short)(r >> 16);
}
// x-tile swizzle (R15): 16-B groups rotated by (row>>3)&7 within 144-B rows
__device__ __forceinline__ int swz(int row, int cb) {
  return row * LDSTR + (cb ^ (((row >> 3) & 7) << 4));
}
// agg-buffer swizzle: full-row XOR within 128-B rows
__device__ __forceinline__ int swa(int row, int cb) {
  return row * 128 + (cb ^ ((row & 7) << 4));
}

// LDS-only barrier: drain lgkmcnt (DS visibility) but NOT vmcnt — the
// nontemporal output stores from the previous tensor keep streaming across
// the barrier instead of serializing at an HBM write-ack drain.
// ("memory" clobber pins the preceding ds_writes before the wait.)
#define BAR_LGKM() do {                                     \
    asm volatile("s_waitcnt lgkmcnt(0)" ::: "memory");      \
    __builtin_amdgcn_s_barrier();                           \
  } while (0)

#define MFMA(a, b, c) __builtin_amdgcn_mfma_f32_16x16x32_bf16(a, b, c, 0, 0, 0)

// (256,3): FINAL occupancy point — 3x confirmed (R5/R9/R16) that 4 waves/EU
// spills. R20 (single variable vs R19): __syncthreads -> lgkmcnt-only
// s_barrier. __syncthreads emits s_waitcnt vmcnt(0) lgkmcnt(0), which makes
// every per-tensor barrier wait for the previous tensor's 16 NT stores to
// commit to HBM (~900cy). Only LDS visibility is actually required.
__global__ __launch_bounds__(256, 3) void gci_kernel(
    const float* __restrict__ x1, const float* __restrict__ x2,
    const float* __restrict__ x3, const float* __restrict__ x4,
    const float* __restrict__ wI, const float* __restrict__ bI,
    const float* __restrict__ wS, const float* __restrict__ bS,
    const float* __restrict__ wG, const float* __restrict__ bG,
    float* __restrict__ out)
{
  // xT0..xT3 (4 x 9216) + agg ping-pong (2 x 8192) = 53248 B -> 3 blocks/CU
  __shared__ __align__(16) char ldsb[4 * TILEB + 2 * 8192];

  const int t    = threadIdx.x;
  const int lane = t & 63;
  const int w    = t >> 6;       // wave id == output-channel group (16 ch)
  const int lr   = lane & 15;
  const int lg   = lane >> 4;

  const int pix0 = blockIdx.x * 64;
  const int b    = pix0 >> 14;          // image index (HW = 16384)
  const int pimg = pix0 & (HW_ - 1);    // pixel offset within image

  const float* xin[4] = {x1, x2, x3, x4};

  // ---------- stage x1..x4 transposed (bf16) into LDS (R15-proven) ----------
  {
    const int pxg = (t & 15) * 4;       // px base
    const int c0  = (t >> 4) * 4;       // channel base
    f32x4 v[16];
    #pragma unroll
    for (int i = 0; i < 4; ++i)
      #pragma unroll
      for (int d = 0; d < 4; ++d)
        v[i * 4 + d] = *reinterpret_cast<const f32x4*>(
            xin[i] + (b * 64 + c0 + d) * HW_ + pimg + pxg);
    #pragma unroll
    for (int i = 0; i < 4; ++i)
      #pragma unroll
      for (int j = 0; j < 4; ++j) {
        u16x4 pk;
        #pragma unroll
        for (int d = 0; d < 4; ++d) pk[d] = f2bf(v[i * 4 + d][j]);
        *(u16x4*)(ldsb + i * TILEB + swz(pxg + j, c0 * 2)) = pk;
      }
  }

  // ---------- this wave's weights: 16 output channels (rows w*16..+15) ----------
  bf16x8 fWi[2], fD[2], fG1[2], fG2[2];
  #pragma unroll
  for (int kk = 0; kk < 2; ++kk) {
    const int row = w * 16 + lr, col = kk * 32 + lg * 8;
    f32x4 wa = *(const f32x4*)(wI + row * 64 + col);
    f32x4 wb = *(const f32x4*)(wI + row * 64 + col + 4);
    f32x4 sa = *(const f32x4*)(wS + row * 64 + col);
    f32x4 sb = *(const f32x4*)(wS + row * 64 + col + 4);
    f32x4 ga = *(const f32x4*)(wG + row * 128 + col);
    f32x4 gb = *(const f32x4*)(wG + row * 128 + col + 4);
    f32x4 ha = *(const f32x4*)(wG + row * 128 + 64 + col);
    f32x4 hb = *(const f32x4*)(wG + row * 128 + 64 + col + 4);
    #pragma unroll
    for (int j = 0; j < 4; ++j) {
      fWi[kk][j]     = (short)f2bf(wa[j]);
      fWi[kk][j + 4] = (short)f2bf(wb[j]);
      fD[kk][j]      = (short)f2bf(sa[j] - wa[j]);
      fD[kk][j + 4]  = (short)f2bf(sb[j] - wb[j]);
      fG1[kk][j]     = (short)f2bf(ga[j]);
      fG1[kk][j + 4] = (short)f2bf(gb[j]);
      fG2[kk][j]     = (short)f2bf(ha[j]);
      fG2[kk][j + 4] = (short)f2bf(hb[j]);
    }
  }

  // biases: C/D row = lg*4 + r  ->  ch = w*16 + lg*4 + r
  f32x4 biasA0, biasG;
  #pragma unroll
  for (int r = 0; r < 4; ++r) {
    const int ch = w * 16 + lg * 4 + r;
    biasA0[r] = bS[ch] + 3.f * bI[ch];
    biasG[r]  = bG[ch];
  }

  BAR_LGKM();   // x-tiles published (ds_writes drained; staging loads already consumed)

  // ---------- Abase[g] = Sum_i Wi*x_i + bias, via MFMA ----------
  f32x4 Abase[4];
  #pragma unroll
  for (int g = 0; g < 4; ++g) {
    Abase[g] = biasA0;
    #pragma unroll
    for (int i = 0; i < 4; ++i) {
      #pragma unroll
      for (int kk = 0; kk < 2; ++kk) {
        bf16x8 f = *(const bf16x8*)(ldsb + i * TILEB + swz(g * 16 + lr, kk * 64 + lg * 16));
        Abase[g] = MFMA(fWi[kk], f, Abase[g]);
      }
    }
  }

  // tensor-0 x fragments
  bf16x8 xB[4][2];
  #pragma unroll
  for (int g = 0; g < 4; ++g)
    #pragma unroll
    for (int kk = 0; kk < 2; ++kk)
      xB[g][kk] = *(const bf16x8*)(ldsb + swz(g * 16 + lr, kk * 64 + lg * 16));

  // ---------- per tensor (software-pipelined xB) ----------
  #pragma unroll
  for (int i = 0; i < 4; ++i) {
    char* tb = ldsb + i * TILEB;
    char* ab = ldsb + AGG0 + (i & 1) * 8192;   // ping-pong agg buffer

    // residual for og[g][r]: x[g*16+lr][w*16+lg*4+r] — one b64 per g
    u16x4 xr[4];
    #pragma unroll
    for (int g = 0; g < 4; ++g)
      xr[g] = *(const u16x4*)(tb + swz(g * 16 + lr, w * 32 + lg * 8));

    // agg = relu(D * x_i + Abase)
    f32x4 agg[4];
    #pragma unroll
    for (int g = 0; g < 4; ++g) {
      agg[g] = Abase[g];
      #pragma unroll
      for (int kk = 0; kk < 2; ++kk) agg[g] = MFMA(fD[kk], xB[g][kk], agg[g]);
    }

    // publish relu(agg) to agg buffer
    #pragma unroll
    for (int g = 0; g < 4; ++g) {
      u16x4 pk;
      #pragma unroll
      for (int r = 0; r < 4; ++r) pk[r] = f2bf(fmaxf(agg[g][r], 0.f));
      *(u16x4*)(ab + swa(g * 16 + lr, w * 32 + lg * 8)) = pk;
    }

    // hoisted gate half: og = biasG + residual + Wg1*x  (barrier-independent)
    f32x4 og[4];
    #pragma unroll
    for (int g = 0; g < 4; ++g) {
      og[g] = biasG;
      #pragma unroll
      for (int r = 0; r < 4; ++r) og[g][r] += bf2f(xr[g][r]);
      #pragma unroll
      for (int kk = 0; kk < 2; ++kk) og[g] = MFMA(fG1[kk], xB[g][kk], og[g]);
    }

    // prefetch next tensor's xB BEFORE the barrier (x-tiles immutable)
    bf16x8 nxB[4][2];
    if (i < 3) {
      char* nb = ldsb + (i + 1) * TILEB;
      #pragma unroll
      for (int g = 0; g < 4; ++g)
        #pragma unroll
        for (int kk = 0; kk < 2; ++kk)
          nxB[g][kk] = *(const bf16x8*)(nb + swz(g * 16 + lr, kk * 64 + lg * 16));
    }

    BAR_LGKM();   // agg published; NT stores from tensor i-1 stay in flight

    // post-barrier: only Wg2 * agg remains on the critical path
    #pragma unroll
    for (int g = 0; g < 4; ++g) {
      bf16x8 aB[2];
      #pragma unroll
      for (int kk = 0; kk < 2; ++kk)
        aB[kk] = *(const bf16x8*)(ab + swa(g * 16 + lr, kk * 64 + lg * 16));
      #pragma unroll
      for (int kk = 0; kk < 2; ++kk) og[g] = MFMA(fG2[kk], aB[kk], og[g]);
    }

    // butterfly 4x4 (lg <-> g) transpose (residual already inside og)
    float B[4][4];
    #pragma unroll
    for (int r = 0; r < 4; ++r) {
      float X0 = og[0][r], X1 = og[1][r], X2 = og[2][r], X3 = og[3][r];
      float s01 = (lg & 1) ? X0 : X1; s01 = __shfl_xor(s01, 16, 64);
      float n0  = (lg & 1) ? s01 : X0;
      float n1  = (lg & 1) ? X1  : s01;
      float s23 = (lg & 1) ? X2 : X3; s23 = __shfl_xor(s23, 16, 64);
      float n2  = (lg & 1) ? s23 : X2;
      float n3  = (lg & 1) ? X3  : s23;
      float u02 = (lg & 2) ? n0 : n2; u02 = __shfl_xor(u02, 32, 64);
      B[r][0]   = (lg & 2) ? u02 : n0;
      B[r][2]   = (lg & 2) ? n2  : u02;
      float u13 = (lg & 2) ? n1 : n3; u13 = __shfl_xor(u13, 32, 64);
      B[r][1]   = (lg & 2) ? u13 : n1;
      B[r][3]   = (lg & 2) ? n3  : u13;
    }

    // stores: pure nontemporal streams, 256 B lines
    const int obase0 = i * 16777216 + b * 64 * HW_ + pimg;
    #pragma unroll
    for (int c = 0; c < 16; ++c)
      __builtin_nontemporal_store(B[c & 3][c >> 2],
                                  &out[obase0 + (w * 16 + c) * HW_ + lane]);

    // rotate pipeline
    if (i < 3) {
      #pragma unroll
      for (int g = 0; g < 4; ++g)
        #pragma unroll
        for (int kk = 0; kk < 2; ++kk)
          xB[g][kk] = nxB[g][kk];
    }
  }
}

extern "C" void kernel_launch(void* const* d_in, const int* in_sizes, int n_in,
                              void* d_out, int out_size, void* d_ws, size_t ws_size,
                              hipStream_t stream) {
  (void)in_sizes; (void)n_in; (void)d_ws; (void)ws_size; (void)out_size;
  gci_kernel<<<dim3(4096), dim3(256), 0, stream>>>(
      (const float*)d_in[0], (const float*)d_in[1],
      (const float*)d_in[2], (const float*)d_in[3],
      (const float*)d_in[4], (const float*)d_in[5],
      (const float*)d_in[6], (const float*)d_in[7],
      (const float*)d_in[8], (const float*)d_in[9],
      (float*)d_out);
}